// Round 7
// baseline (25.850 us; speedup 1.0000x reference)
//
#include <hip/hip_runtime.h>
#include <math.h>

// Problem constants (from reference init)
#define NB     16      // N
#define PB     4       // P
#define LTAPS  16      // L
#define SS     128     // S = Ns + N_pilot
#define MM     1024    // Mk = OPT_M

#define TWO_PI_F 6.28318530717958647692f

#define HT_BLKS     256                  // 256*256 = 65536 = NB*PB*MM (run FIRST)
#define STREAM_BLKS 2048                 // 2048 blocks * 2048 float4 = TOT4
#define TOT4 (NB * PB * SS * MM / 2)     // 4194304 float4

typedef float f32x4 __attribute__((ext_vector_type(4)));

// ---------------------------------------------------------------------------
// Single fused kernel, HT blocks FIRST so their VALU-bound work overlaps the
// memory-bound streaming blocks instead of forming a serialized tail.
//
//  blocks [0, HT_BLKS):  H_t[np,k] = sum_l cof[l] * w^l, w = exp(-2pi*i*k/M)
//      (1 fast sincos + 15 complex FMAs via power recurrence)
//  blocks [HT_BLKS, +STREAM_BLKS): contiguous 2048-float4 chunk per block
//      = 4 consecutive (np,s) rows. 2x4-deep load pipeline (keeps VGPR <= 64
//      for 8 waves/SIMD occupancy); factors computed redundantly per-wave
//      with fast-math transcendentals + __shfl reduce (no LDS, no barriers).
// ---------------------------------------------------------------------------
__global__ __launch_bounds__(256, 8) void fused_kernel(
    const float* __restrict__ in,   // (N,P,S*M,2) f32
    const float* __restrict__ cof,  // (N,P,L)    f32, strictly positive
    float* __restrict__ out,        // (N,P,S*M,2) f32
    float* __restrict__ ht)         // (N,P,M,2)  f32
{
    const int b = blockIdx.x;
    const int t = threadIdx.x;

    if (b >= HT_BLKS) {
        const int sb = b - HT_BLKS;              // streaming block id
        const f32x4* __restrict__ in4  = (const f32x4*)in + (size_t)sb * 2048;
        f32x4* __restrict__       out4 = (f32x4*)out      + (size_t)sb * 2048;

        // ---- batch 0: issue 4 loads (independent of factor preamble) ----
        f32x4 v0[4];
#pragma unroll
        for (int k = 0; k < 4; ++k)
            v0[k] = __builtin_nontemporal_load(&in4[k * 256 + t]);

        // ---- per-wave redundant factor computation (barrier-free) ----
        // lane = (j,l): j = which of the 4 (np,s) rows, l = tap index
        const int lane = t & 63;
        const int j    = lane >> 4;
        const int l    = lane & 15;
        const int id   = sb * 4 + j;             // flattened (np,s), < 8192
        const int np   = id >> 7;
        const int s    = id & (SS - 1);
        const float cofl   = cof[np * LTAPS + l];
        const float delay1 = (-100.0f / 3.0e8f) * __logf(cofl);
        const float delay2 = (0.0005f / 14.0f) * (float)s;
        const float pc     = TWO_PI_F * 1000.0f * __cosf((TWO_PI_F / 15.0f) * (float)l);
        const float ph     = pc * (delay1 + delay2);
        float sn, cs;
        __sincosf(ph, &sn, &cs);
        float re = cofl * cs;
        float im = -cofl * sn;
#pragma unroll
        for (int w = 1; w < 16; w <<= 1) {       // 16-tap reduce per group
            re += __shfl_xor(re, w);
            im += __shfl_xor(im, w);
        }
        float fre[4], fim[4];
#pragma unroll
        for (int jj = 0; jj < 4; ++jj) {         // broadcast 4 group sums
            fre[jj] = __shfl(re, jj * 16);
            fim[jj] = __shfl(im, jj * 16);
        }

        // ---- batch 1: issue next 4 loads, then process batch 0 ----
        f32x4 v1[4];
#pragma unroll
        for (int k = 0; k < 4; ++k)
            v1[k] = __builtin_nontemporal_load(&in4[(k + 4) * 256 + t]);

#pragma unroll
        for (int k = 0; k < 4; ++k) {
            const int jj = k >> 1;               // 512 float4 per (np,s)
            f32x4 r;
            r.x = v0[k].x * fre[jj] - v0[k].y * fim[jj];
            r.y = v0[k].x * fim[jj] + v0[k].y * fre[jj];
            r.z = v0[k].z * fre[jj] - v0[k].w * fim[jj];
            r.w = v0[k].z * fim[jj] + v0[k].w * fre[jj];
            __builtin_nontemporal_store(r, &out4[k * 256 + t]);
        }
#pragma unroll
        for (int k = 0; k < 4; ++k) {
            const int jj = (k + 4) >> 1;
            f32x4 r;
            r.x = v1[k].x * fre[jj] - v1[k].y * fim[jj];
            r.y = v1[k].x * fim[jj] + v1[k].y * fre[jj];
            r.z = v1[k].z * fre[jj] - v1[k].w * fim[jj];
            r.w = v1[k].z * fim[jj] + v1[k].w * fre[jj];
            __builtin_nontemporal_store(r, &out4[(k + 4) * 256 + t]);
        }
    } else {
        const int id = b * 256 + t;              // (np, k)
        const int np = id >> 10;
        const int k  = id & (MM - 1);
        float sn, cs;
        __sincosf((TWO_PI_F / (float)MM) * (float)k, &sn, &cs);
        const float wr = cs, wi = -sn;           // w = exp(-2*pi*i*k/M)
        const float* __restrict__ c = cof + np * LTAPS;
        float hr = 0.0f, hi = 0.0f;              // H accumulator
        float cr = 1.0f, ci = 0.0f;              // w^l
#pragma unroll
        for (int l = 0; l < LTAPS; ++l) {
            const float cl = c[l];
            hr += cl * cr;
            hi += cl * ci;
            const float nr = cr * wr - ci * wi;
            const float ni = cr * wi + ci * wr;
            cr = nr; ci = ni;
        }
        float2* __restrict__ o = (float2*)ht;
        o[id] = make_float2(hr, hi);
    }
}

// ---------------------------------------------------------------------------
extern "C" void kernel_launch(void* const* d_in, const int* in_sizes, int n_in,
                              void* d_out, int out_size, void* d_ws, size_t ws_size,
                              hipStream_t stream)
{
    const float* in  = (const float*)d_in[0];   // input_ri (N,P,S*M,2)
    const float* cof = (const float*)d_in[1];   // cof (N,P,L)
    float* out = (float*)d_out;                              // out_ri first
    float* ht  = out + (size_t)NB * PB * SS * MM * 2;        // then H_t_ri

    hipLaunchKernelGGL(fused_kernel, dim3(HT_BLKS + STREAM_BLKS), dim3(256), 0, stream,
                       in, cof, out, ht);
}